// Round 2
// baseline (1027.352 us; speedup 1.0000x reference)
//
#include <hip/hip_runtime.h>
#include <hip/hip_bf16.h>

#define B_ 4
#define S_ 4096
#define D_ 1024
#define DH_ 128

static constexpr float SCALE2 = 0.08838834764831845f * 1.4426950408889634f; // log2(e)/sqrt(DH)

typedef __attribute__((ext_vector_type(8))) short s8v;   // 8 bf16
typedef __attribute__((ext_vector_type(4))) short s4v;   // 4 bf16
typedef __attribute__((ext_vector_type(4))) float f4v;   // MFMA acc

__device__ inline short f2bf(float f) {
  __hip_bfloat16 h = __float2bfloat16(f);
  return *reinterpret_cast<short*>(&h);
}

#if __has_builtin(__builtin_amdgcn_exp2f)
__device__ inline float fexp2(float x) { return __builtin_amdgcn_exp2f(x); }
#else
__device__ inline float fexp2(float x) { return __expf(x * 0.6931471805599453f); }
#endif

// ---------------- prep: zero outp accumulator + convert Wm to bf16 ----------------
__global__ void prep_kernel(const float* __restrict__ Wm, short* __restrict__ wmb,
                            float4* __restrict__ outp4) {
  int id = blockIdx.x * 256 + threadIdx.x;
  if (id < (B_ * S_ * DH_) / 4) outp4[id] = make_float4(0.f, 0.f, 0.f, 0.f);
  if (id < (DH_ * 2 * DH_) / 4) {
    float4 w = reinterpret_cast<const float4*>(Wm)[id];
    s4v h; h[0] = f2bf(w.x); h[1] = f2bf(w.y); h[2] = f2bf(w.z); h[3] = f2bf(w.w);
    reinterpret_cast<s4v*>(wmb)[id] = h;
  }
}

// ---------------- projections: y[M,128] = X[M,1024] @ W[128,1024]^T (bf16 out) ----------------
__global__ __launch_bounds__(256) void proj3_kernel(const float* __restrict__ Xq,
                                                    const float* __restrict__ Xk,
                                                    const float* __restrict__ Xv,
                                                    const float* __restrict__ Wq,
                                                    const float* __restrict__ Wk,
                                                    const float* __restrict__ Wv,
                                                    short* __restrict__ qw,
                                                    short* __restrict__ kw,
                                                    short* __restrict__ vw) {
  __shared__ short Xs[64][72];
  __shared__ short Ws[128][72];
  const int which = blockIdx.y;
  const float* X; const float* W; short* out;
  if (which == 0)      { X = Xq; W = Wq; out = qw; }
  else if (which == 1) { X = Xk; W = Wk; out = kw; }
  else                 { X = Xv; W = Wv; out = vw; }

  const int tid = threadIdx.x;
  const int wv = tid >> 6, lane = tid & 63;
  const int lrow = lane & 15, lgrp = lane >> 4;
  const int r0 = blockIdx.x * 64;

  f4v acc[8];
#pragma unroll
  for (int i = 0; i < 8; i++) acc[i] = (f4v){0.f, 0.f, 0.f, 0.f};

  for (int kk = 0; kk < D_; kk += 64) {
    {
      int row = tid >> 2, cb = (tid & 3) * 16;
      const float* src = X + (size_t)(r0 + row) * D_ + kk + cb;
#pragma unroll
      for (int i = 0; i < 4; i++) {
        float4 v = *reinterpret_cast<const float4*>(src + i * 4);
        s4v h; h[0] = f2bf(v.x); h[1] = f2bf(v.y); h[2] = f2bf(v.z); h[3] = f2bf(v.w);
        *reinterpret_cast<s4v*>(&Xs[row][cb + i * 4]) = h;
      }
    }
    {
      int row = tid >> 1, cb = (tid & 1) * 32;
      const float* src = W + (size_t)row * D_ + kk + cb;
#pragma unroll
      for (int i = 0; i < 8; i++) {
        float4 v = *reinterpret_cast<const float4*>(src + i * 4);
        s4v h; h[0] = f2bf(v.x); h[1] = f2bf(v.y); h[2] = f2bf(v.z); h[3] = f2bf(v.w);
        *reinterpret_cast<s4v*>(&Ws[row][cb + i * 4]) = h;
      }
    }
    __syncthreads();
#pragma unroll
    for (int ks = 0; ks < 2; ks++) {
      s8v a = *reinterpret_cast<const s8v*>(&Xs[wv * 16 + lrow][ks * 32 + lgrp * 8]);
#pragma unroll
      for (int nf = 0; nf < 8; nf++) {
        s8v b = *reinterpret_cast<const s8v*>(&Ws[nf * 16 + lrow][ks * 32 + lgrp * 8]);
        acc[nf] = __builtin_amdgcn_mfma_f32_16x16x32_bf16(a, b, acc[nf], 0, 0, 0);
      }
    }
    __syncthreads();
  }
#pragma unroll
  for (int nf = 0; nf < 8; nf++)
#pragma unroll
    for (int r = 0; r < 4; r++) {
      int row = r0 + wv * 16 + lgrp * 4 + r;
      out[(size_t)row * DH_ + nf * 16 + lrow] = f2bf(acc[nf][r]);
    }
}

// ---------------- cvt[b*128+g][s] = (v @ (0.2 I + 0.48 Wp + 0.32 Wt)^T)^T  (f32, transposed) ----------------
__global__ __launch_bounds__(256) void cv_kernel(const short* __restrict__ vw,
                                                 const float* __restrict__ Wp,
                                                 const float* __restrict__ Wt,
                                                 float* __restrict__ cvt) {
  __shared__ short Ws[128][136];
  const int tid = threadIdx.x;
  const int wv = tid >> 6, lane = tid & 63;
  const int lrow = lane & 15, lgrp = lane >> 4;
  const int r0 = blockIdx.x * 64;

  {
    int g = tid >> 1, cb = (tid & 1) * 64;
#pragma unroll
    for (int i = 0; i < 16; i++) {
      int c = cb + i * 4;
      float4 p4 = *reinterpret_cast<const float4*>(&Wp[(size_t)g * DH_ + c]);
      float4 t4 = *reinterpret_cast<const float4*>(&Wt[(size_t)g * DH_ + c]);
      s4v h;
      h[0] = f2bf(0.48f * p4.x + 0.32f * t4.x + ((c + 0) == g ? 0.2f : 0.f));
      h[1] = f2bf(0.48f * p4.y + 0.32f * t4.y + ((c + 1) == g ? 0.2f : 0.f));
      h[2] = f2bf(0.48f * p4.z + 0.32f * t4.z + ((c + 2) == g ? 0.2f : 0.f));
      h[3] = f2bf(0.48f * p4.w + 0.32f * t4.w + ((c + 3) == g ? 0.2f : 0.f));
      *reinterpret_cast<s4v*>(&Ws[g][c]) = h;
    }
  }
  __syncthreads();

  s8v av[4];
#pragma unroll
  for (int ks = 0; ks < 4; ks++)
    av[ks] = *reinterpret_cast<const s8v*>(&vw[(size_t)(r0 + wv * 16 + lrow) * DH_ + ks * 32 + lgrp * 8]);

  f4v acc[8];
#pragma unroll
  for (int i = 0; i < 8; i++) acc[i] = (f4v){0.f, 0.f, 0.f, 0.f};
#pragma unroll
  for (int ks = 0; ks < 4; ks++)
#pragma unroll
    for (int nf = 0; nf < 8; nf++) {
      s8v b = *reinterpret_cast<const s8v*>(&Ws[nf * 16 + lrow][ks * 32 + lgrp * 8]);
      acc[nf] = __builtin_amdgcn_mfma_f32_16x16x32_bf16(av[ks], b, acc[nf], 0, 0, 0);
    }

  // write transposed: cvt[(b*128+g)][s], 4 consecutive s per lane
  const int grow = r0 + wv * 16 + lgrp * 4;
  const int bb = grow >> 12, s = grow & (S_ - 1);
#pragma unroll
  for (int nf = 0; nf < 8; nf++) {
    int g = nf * 16 + lrow;
    float4 v4 = make_float4(acc[nf][0], acc[nf][1], acc[nf][2], acc[nf][3]);
    *reinterpret_cast<float4*>(&cvt[((size_t)(bb * DH_ + g)) * S_ + s]) = v4;
  }
}

// ---------------- cv2t[row][s] = bf16(0.3 cvt[s] + 0.49 cvt[s+1] + 0.21 cvt[s+1024]) ----------------
__global__ void cv2t_kernel(const float* __restrict__ cvt, short* __restrict__ cv2t) {
  int id = blockIdx.x * 256 + threadIdx.x;      // B*DH*S/4 = 524288
  int s = (id & 1023) * 4;
  int row = id >> 10;                            // 512 rows
  const float* src = cvt + (size_t)row * S_;
  float4 a = *reinterpret_cast<const float4*>(src + s);
  float b1 = src[(s + 4) & (S_ - 1)];
  float4 c = *reinterpret_cast<const float4*>(src + ((s + 1024) & (S_ - 1)));
  s4v o;
  o[0] = f2bf(0.3f * a.x + 0.49f * a.y + 0.21f * c.x);
  o[1] = f2bf(0.3f * a.y + 0.49f * a.z + 0.21f * c.y);
  o[2] = f2bf(0.3f * a.z + 0.49f * a.w + 0.21f * c.z);
  o[3] = f2bf(0.3f * a.w + 0.49f * b1  + 0.21f * c.w);
  *reinterpret_cast<s4v*>(&cv2t[(size_t)row * S_ + s]) = o;
}

// ---------------- pass A: column-split softmax stats (base-2 domain) ----------------
__global__ __launch_bounds__(256) void stats_kernel(const short* __restrict__ qw,
                                                    const short* __restrict__ kw,
                                                    float* __restrict__ spart) {
  const int tid = threadIdx.x;
  const int wv = tid >> 6, lane = tid & 63;
  const int lrow = lane & 15, lgrp = lane >> 4;
  const int combo = blockIdx.x, qt = blockIdx.y;
  const int b = combo >> 2, cq = combo & 3;
  const int rowbase = qt * 64 + wv * 16;
  const short* qb = qw + (size_t)b * S_ * DH_;
  const short* kb = kw + (size_t)b * S_ * DH_;

  s8v qa[4];
#pragma unroll
  for (int ks = 0; ks < 4; ks++)
    qa[ks] = *reinterpret_cast<const s8v*>(&qb[(size_t)(rowbase + lrow) * DH_ + ks * 32 + lgrp * 8]);

  float ml[4], ll[4];
#pragma unroll
  for (int r = 0; r < 4; r++) { ml[r] = -1e30f; ll[r] = 0.f; }

  for (int ct = 0; ct < 16; ct++) {
    int c0 = cq * 1024 + ct * 64;
    f4v sacc[4];
#pragma unroll
    for (int i = 0; i < 4; i++) sacc[i] = (f4v){0.f, 0.f, 0.f, 0.f};
#pragma unroll
    for (int nf = 0; nf < 4; nf++) {
      const short* krow = kb + (size_t)(c0 + nf * 16 + lrow) * DH_;
#pragma unroll
      for (int ks = 0; ks < 4; ks++) {
        s8v bf = *reinterpret_cast<const s8v*>(krow + ks * 32 + lgrp * 8);
        sacc[nf] = __builtin_amdgcn_mfma_f32_16x16x32_bf16(qa[ks], bf, sacc[nf], 0, 0, 0);
      }
    }
#pragma unroll
    for (int r = 0; r < 4; r++) {
      float t0 = sacc[0][r] * SCALE2, t1 = sacc[1][r] * SCALE2;
      float t2 = sacc[2][r] * SCALE2, t3 = sacc[3][r] * SCALE2;
      float mx = fmaxf(fmaxf(t0, t1), fmaxf(t2, t3));
      float mn = fmaxf(ml[r], mx);
      ll[r] = ll[r] * fexp2(ml[r] - mn)
            + fexp2(t0 - mn) + fexp2(t1 - mn) + fexp2(t2 - mn) + fexp2(t3 - mn);
      ml[r] = mn;
    }
  }
  // cross-lane merge over the 16 lanes holding this row's columns
#pragma unroll
  for (int r = 0; r < 4; r++) {
#pragma unroll
    for (int off = 1; off < 16; off <<= 1) {
      float om = __shfl_xor(ml[r], off);
      float ol = __shfl_xor(ll[r], off);
      float mn = fmaxf(ml[r], om);
      ll[r] = ll[r] * fexp2(ml[r] - mn) + ol * fexp2(om - mn);
      ml[r] = mn;
    }
  }
  if (lrow == 0) {
#pragma unroll
    for (int r = 0; r < 4; r++) {
      int row = rowbase + lgrp * 4 + r;
      size_t idx = (((size_t)b * S_ + row) * 4 + cq) * 2;
      spart[idx] = ml[r];
      spart[idx + 1] = ll[r];
    }
  }
}

__global__ void statcomb_kernel(const float* __restrict__ spart, float* __restrict__ statf) {
  int row = blockIdx.x * 256 + threadIdx.x; // 16384 rows
  float mm[4], ll[4];
  float m = -1e30f;
#pragma unroll
  for (int i = 0; i < 4; i++) {
    mm[i] = spart[((size_t)row * 4 + i) * 2];
    ll[i] = spart[((size_t)row * 4 + i) * 2 + 1];
    m = fmaxf(m, mm[i]);
  }
  float L = 0.f;
#pragma unroll
  for (int i = 0; i < 4; i++) L += ll[i] * fexp2(mm[i] - m);
  statf[(size_t)row * 2] = m;
  statf[(size_t)row * 2 + 1] = 1.0f / L;
}

// ---------------- pass B: vortex_attn write + out accumulation ----------------
__global__ __launch_bounds__(256) void vortex_kernel(const short* __restrict__ qw,
                                                     const short* __restrict__ kw,
                                                     const short* __restrict__ cv2t,
                                                     const float* __restrict__ statf,
                                                     float* __restrict__ vout,
                                                     float* __restrict__ outp) {
  __shared__ short palds[4][16][72]; // per-wave bf16 P tile for PV A-operand
  const int tid = threadIdx.x;
  const int wv = tid >> 6, lane = tid & 63;
  const int lrow = lane & 15, lgrp = lane >> 4;
  const int lastlane = (lane & 48) | 15;
  const int ch = blockIdx.x, qt = blockIdx.y, b = blockIdx.z;
  const int rowb = qt * 64 + wv * 16;

  const short* qb = qw + (size_t)b * S_ * DH_;
  const short* kb = kw + (size_t)b * S_ * DH_;

  s8v qa[4];
#pragma unroll
  for (int ks = 0; ks < 4; ks++)
    qa[ks] = *reinterpret_cast<const s8v*>(&qb[(size_t)(rowb + lrow) * DH_ + ks * 32 + lgrp * 8]);

  float m2[4], rcl[4];
#pragma unroll
  for (int r = 0; r < 4; r++) {
    int row = rowb + lgrp * 4 + r;
    m2[r]  = statf[((size_t)b * S_ + row) * 2];
    rcl[r] = statf[((size_t)b * S_ + row) * 2 + 1];
  }

  f4v o[8];
#pragma unroll
  for (int i = 0; i < 8; i++) o[i] = (f4v){0.f, 0.f, 0.f, 0.f};

  const int cc0 = ch * 512;
  float carry[4];

  // boundary fragment: columns cc0-16 .. cc0-1 (wrapped); extract col cc0-1
  {
    f4v pacc = (f4v){0.f, 0.f, 0.f, 0.f};
    const short* krow = kb + (size_t)((cc0 - 16 + lrow) & (S_ - 1)) * DH_;
#pragma unroll
    for (int ks = 0; ks < 4; ks++) {
      s8v bf = *reinterpret_cast<const s8v*>(krow + ks * 32 + lgrp * 8);
      pacc = __builtin_amdgcn_mfma_f32_16x16x32_bf16(qa[ks], bf, pacc, 0, 0, 0);
    }
#pragma unroll
    for (int r = 0; r < 4; r++) {
      float pb = fexp2(pacc[r] * SCALE2 - m2[r]) * rcl[r];
      carry[r] = __shfl(pb, lastlane);
    }
  }

  for (int ct = 0; ct < 8; ct++) {
    const int c0 = cc0 + ct * 64;
    f4v sa[4], sc[4];
#pragma unroll
    for (int i = 0; i < 4; i++) { sa[i] = (f4v){0.f,0.f,0.f,0.f}; sc[i] = (f4v){0.f,0.f,0.f,0.f}; }
#pragma unroll
    for (int nf = 0; nf < 4; nf++) {
      const short* krA = kb + (size_t)(c0 + nf * 16 + lrow) * DH_;
      const short* krC = kb + (size_t)((c0 + nf * 16 + lrow + 3072) & (S_ - 1)) * DH_;
#pragma unroll
      for (int ks = 0; ks < 4; ks++) {
        s8v bA = *reinterpret_cast<const s8v*>(krA + ks * 32 + lgrp * 8);
        sa[nf] = __builtin_amdgcn_mfma_f32_16x16x32_bf16(qa[ks], bA, sa[nf], 0, 0, 0);
        s8v bC = *reinterpret_cast<const s8v*>(krC + ks * 32 + lgrp * 8);
        sc[nf] = __builtin_amdgcn_mfma_f32_16x16x32_bf16(qa[ks], bC, sc[nf], 0, 0, 0);
      }
    }
    float pa[4][4], pc[4][4];
#pragma unroll
    for (int nf = 0; nf < 4; nf++)
#pragma unroll
      for (int r = 0; r < 4; r++) {
        pa[nf][r] = fexp2(sa[nf][r] * SCALE2 - m2[r]) * rcl[r];
        pc[nf][r] = fexp2(sc[nf][r] * SCALE2 - m2[r]) * rcl[r];
        palds[wv][lgrp * 4 + r][nf * 16 + lrow] = f2bf(pa[nf][r]);
      }
    // vortex_attn: 0.3*p[c] + 0.49*p[c-1] + 0.21*p[c-1024 mod S]
#pragma unroll
    for (int nf = 0; nf < 4; nf++)
#pragma unroll
      for (int r = 0; r < 4; r++) {
        float left = __shfl_up(pa[nf][r], 1);
        float pl = (nf == 0) ? carry[r] : __shfl(pa[nf - 1][r], lastlane);
        float sh = (lrow == 0) ? pl : left;
        float val = 0.3f * pa[nf][r] + 0.49f * sh + 0.21f * pc[nf][r];
        vout[((size_t)(b * S_ + rowb + lgrp * 4 + r)) * S_ + c0 + nf * 16 + lrow] = val;
      }
#pragma unroll
    for (int r = 0; r < 4; r++) carry[r] = __shfl(pa[3][r], lastlane);

    // ensure P-tile LDS writes are visible before cross-lane reads
    asm volatile("s_waitcnt lgkmcnt(0)" ::: "memory");

    // PV: out += P @ cv2
#pragma unroll
    for (int ks2 = 0; ks2 < 2; ks2++) {
      s8v a = *reinterpret_cast<const s8v*>(&palds[wv][lrow][ks2 * 32 + lgrp * 8]);
#pragma unroll
      for (int gf = 0; gf < 8; gf++) {
        s8v bfr = *reinterpret_cast<const s8v*>(
            &cv2t[((size_t)(b * DH_ + gf * 16 + lrow)) * S_ + c0 + ks2 * 32 + lgrp * 8]);
        o[gf] = __builtin_amdgcn_mfma_f32_16x16x32_bf16(a, bfr, o[gf], 0, 0, 0);
      }
    }
  }
#pragma unroll
  for (int gf = 0; gf < 8; gf++)
#pragma unroll
    for (int r = 0; r < 4; r++)
      atomicAdd(&outp[((size_t)(b * S_ + rowb + lgrp * 4 + r)) * DH_ + gf * 16 + lrow], o[gf][r]);
}

// ---------------- gate GEMM + final blend ----------------
__global__ __launch_bounds__(256) void gate_kernel(const float* __restrict__ outp,
                                                   const float* __restrict__ prev,
                                                   const short* __restrict__ wmb,
                                                   const float* __restrict__ bm,
                                                   float* __restrict__ dout) {
  __shared__ short As[64][264];
  const int tid = threadIdx.x;
  const int wv = tid >> 6, lane = tid & 63;
  const int lrow = lane & 15, lgrp = lane >> 4;
  const int r0 = blockIdx.x * 64;
  {
    int row = tid >> 2, seg = (tid & 3) * 64;
#pragma unroll
    for (int i = 0; i < 16; i++) {
      int c = seg + i * 4;
      float4 v;
      if (c < 128) v = *reinterpret_cast<const float4*>(&outp[(size_t)(r0 + row) * DH_ + c]);
      else         v = *reinterpret_cast<const float4*>(&prev[(size_t)(r0 + row) * DH_ + (c - 128)]);
      s4v h; h[0] = f2bf(v.x); h[1] = f2bf(v.y); h[2] = f2bf(v.z); h[3] = f2bf(v.w);
      *reinterpret_cast<s4v*>(&As[row][c]) = h;
    }
  }
  __syncthreads();
  f4v g[8];
#pragma unroll
  for (int i = 0; i < 8; i++) g[i] = (f4v){0.f, 0.f, 0.f, 0.f};
#pragma unroll
  for (int ks = 0; ks < 8; ks++) {
    s8v a = *reinterpret_cast<const s8v*>(&As[wv * 16 + lrow][ks * 32 + lgrp * 8]);
#pragma unroll
    for (int nf = 0; nf < 8; nf++) {
      s8v bfr = *reinterpret_cast<const s8v*>(&wmb[(size_t)(nf * 16 + lrow) * 256 + ks * 32 + lgrp * 8]);
      g[nf] = __builtin_amdgcn_mfma_f32_16x16x32_bf16(a, bfr, g[nf], 0, 0, 0);
    }
  }
#pragma unroll
  for (int nf = 0; nf < 8; nf++)
#pragma unroll
    for (int r = 0; r < 4; r++) {
      int h = nf * 16 + lrow;
      int row = r0 + wv * 16 + lgrp * 4 + r;
      float pre = g[nf][r] + bm[h];
      float gate = 1.0f / (1.0f + fexp2(-1.4426950408889634f * pre));
      float op = outp[(size_t)row * DH_ + h];
      float pv = prev[(size_t)row * DH_ + h];
      dout[(size_t)row * DH_ + h] = 0.9f * gate * pv + 0.1f * op;
    }
}

extern "C" void kernel_launch(void* const* d_in, const int* in_sizes, int n_in,
                              void* d_out, int out_size, void* d_ws, size_t ws_size,
                              hipStream_t stream) {
  (void)in_sizes; (void)n_in; (void)out_size; (void)ws_size;
  const float* query = (const float*)d_in[0];
  const float* key   = (const float*)d_in[1];
  const float* value = (const float*)d_in[2];
  const float* prev  = (const float*)d_in[3];
  const float* Wq = (const float*)d_in[4];
  const float* Wk = (const float*)d_in[5];
  const float* Wv = (const float*)d_in[6];
  const float* Wp = (const float*)d_in[7];
  const float* Wt = (const float*)d_in[8];
  const float* Wm = (const float*)d_in[9];
  const float* bm = (const float*)d_in[10];

  char* ws = (char*)d_ws;
  short* qw    = (short*)(ws);                  // [B*S,128] bf16   4 MB
  short* kw    = (short*)(ws + 4194304);        // [B*S,128] bf16   4 MB
  short* vw    = (short*)(ws + 8388608);        // [B*S,128] bf16   4 MB
  float* cvt   = (float*)(ws + 12582912);       // [B*128,S] f32    8 MB (transposed cv)
  short* cv2t  = (short*)(ws + 20971520);       // [B*128,S] bf16   4 MB
  float* spart = (float*)(ws + 25165824);       // [B*S,4,2] f32    512 KB
  float* statf = (float*)(ws + 25690112);       // [B*S,2]   f32    128 KB
  short* wmb   = (short*)(ws + 25821184);       // [128,256] bf16   64 KB
  float* outp  = (float*)(ws + 25886720);       // [B*S,128] f32    8 MB

  float* out_final  = (float*)d_out;
  float* vortex_out = (float*)d_out + (size_t)B_ * S_ * DH_;

  prep_kernel<<<2048, 256, 0, stream>>>(Wm, wmb, (float4*)outp);
  proj3_kernel<<<dim3(256, 3), 256, 0, stream>>>(query, key, value, Wq, Wk, Wv, qw, kw, vw);
  cv_kernel<<<256, 256, 0, stream>>>(vw, Wp, Wt, cvt);
  cv2t_kernel<<<2048, 256, 0, stream>>>(cvt, cv2t);
  stats_kernel<<<dim3(16, 64), 256, 0, stream>>>(qw, kw, spart);
  statcomb_kernel<<<64, 256, 0, stream>>>(spart, statf);
  vortex_kernel<<<dim3(8, 64, B_), 256, 0, stream>>>(qw, kw, cv2t, statf, vortex_out, outp);
  gate_kernel<<<256, 256, 0, stream>>>(outp, prev, wmb, bm, out_final);
}

// Round 3
// 950.102 us; speedup vs baseline: 1.0813x; 1.0813x over previous
//
#include <hip/hip_runtime.h>
#include <hip/hip_bf16.h>

#define B_ 4
#define S_ 4096
#define D_ 1024
#define DH_ 128

static constexpr float SCALE2 = 0.08838834764831845f * 1.4426950408889634f; // log2(e)/sqrt(DH)

typedef __attribute__((ext_vector_type(8))) short s8v;   // 8 bf16
typedef __attribute__((ext_vector_type(4))) short s4v;   // 4 bf16
typedef __attribute__((ext_vector_type(4))) float f4v;   // MFMA acc

__device__ inline short f2bf(float f) {
  __hip_bfloat16 h = __float2bfloat16(f);
  return *reinterpret_cast<short*>(&h);
}

#if __has_builtin(__builtin_amdgcn_exp2f)
__device__ inline float fexp2(float x) { return __builtin_amdgcn_exp2f(x); }
#else
__device__ inline float fexp2(float x) { return __expf(x * 0.6931471805599453f); }
#endif

// ---------------- prep: zero outp accumulator + convert Wm to bf16 ----------------
__global__ void prep_kernel(const float* __restrict__ Wm, short* __restrict__ wmb,
                            float4* __restrict__ outp4) {
  int id = blockIdx.x * 256 + threadIdx.x;
  if (id < (B_ * S_ * DH_) / 4) outp4[id] = make_float4(0.f, 0.f, 0.f, 0.f);
  if (id < (DH_ * 2 * DH_) / 4) {
    float4 w = reinterpret_cast<const float4*>(Wm)[id];
    s4v h; h[0] = f2bf(w.x); h[1] = f2bf(w.y); h[2] = f2bf(w.z); h[3] = f2bf(w.w);
    reinterpret_cast<s4v*>(wmb)[id] = h;
  }
}

// ---------------- projections: y[M,128] = X[M,1024] @ W[128,1024]^T (bf16 out) ----------------
__global__ __launch_bounds__(256) void proj3_kernel(const float* __restrict__ Xq,
                                                    const float* __restrict__ Xk,
                                                    const float* __restrict__ Xv,
                                                    const float* __restrict__ Wq,
                                                    const float* __restrict__ Wk,
                                                    const float* __restrict__ Wv,
                                                    short* __restrict__ qw,
                                                    short* __restrict__ kw,
                                                    short* __restrict__ vw) {
  __shared__ short Xs[64][72];
  __shared__ short Ws[128][72];
  const int which = blockIdx.y;
  const float* X; const float* W; short* out;
  if (which == 0)      { X = Xq; W = Wq; out = qw; }
  else if (which == 1) { X = Xk; W = Wk; out = kw; }
  else                 { X = Xv; W = Wv; out = vw; }

  const int tid = threadIdx.x;
  const int wv = tid >> 6, lane = tid & 63;
  const int lrow = lane & 15, lgrp = lane >> 4;
  const int r0 = blockIdx.x * 64;

  f4v acc[8];
#pragma unroll
  for (int i = 0; i < 8; i++) acc[i] = (f4v){0.f, 0.f, 0.f, 0.f};

  for (int kk = 0; kk < D_; kk += 64) {
    {
      int row = tid >> 2, cb = (tid & 3) * 16;
      const float* src = X + (size_t)(r0 + row) * D_ + kk + cb;
#pragma unroll
      for (int i = 0; i < 4; i++) {
        float4 v = *reinterpret_cast<const float4*>(src + i * 4);
        s4v h; h[0] = f2bf(v.x); h[1] = f2bf(v.y); h[2] = f2bf(v.z); h[3] = f2bf(v.w);
        *reinterpret_cast<s4v*>(&Xs[row][cb + i * 4]) = h;
      }
    }
    {
      int row = tid >> 1, cb = (tid & 1) * 32;
      const float* src = W + (size_t)row * D_ + kk + cb;
#pragma unroll
      for (int i = 0; i < 8; i++) {
        float4 v = *reinterpret_cast<const float4*>(src + i * 4);
        s4v h; h[0] = f2bf(v.x); h[1] = f2bf(v.y); h[2] = f2bf(v.z); h[3] = f2bf(v.w);
        *reinterpret_cast<s4v*>(&Ws[row][cb + i * 4]) = h;
      }
    }
    __syncthreads();
#pragma unroll
    for (int ks = 0; ks < 2; ks++) {
      s8v a = *reinterpret_cast<const s8v*>(&Xs[wv * 16 + lrow][ks * 32 + lgrp * 8]);
#pragma unroll
      for (int nf = 0; nf < 8; nf++) {
        s8v b = *reinterpret_cast<const s8v*>(&Ws[nf * 16 + lrow][ks * 32 + lgrp * 8]);
        acc[nf] = __builtin_amdgcn_mfma_f32_16x16x32_bf16(a, b, acc[nf], 0, 0, 0);
      }
    }
    __syncthreads();
  }
#pragma unroll
  for (int nf = 0; nf < 8; nf++)
#pragma unroll
    for (int r = 0; r < 4; r++) {
      int row = r0 + wv * 16 + lgrp * 4 + r;
      out[(size_t)row * DH_ + nf * 16 + lrow] = f2bf(acc[nf][r]);
    }
}

// ---------------- cvt[b*128+g][s] = (v @ (0.2 I + 0.48 Wp + 0.32 Wt)^T)^T  (f32, transposed) ----------------
__global__ __launch_bounds__(256) void cv_kernel(const short* __restrict__ vw,
                                                 const float* __restrict__ Wp,
                                                 const float* __restrict__ Wt,
                                                 float* __restrict__ cvt) {
  __shared__ short Ws[128][136];
  const int tid = threadIdx.x;
  const int wv = tid >> 6, lane = tid & 63;
  const int lrow = lane & 15, lgrp = lane >> 4;
  const int r0 = blockIdx.x * 64;

  {
    int g = tid >> 1, cb = (tid & 1) * 64;
#pragma unroll
    for (int i = 0; i < 16; i++) {
      int c = cb + i * 4;
      float4 p4 = *reinterpret_cast<const float4*>(&Wp[(size_t)g * DH_ + c]);
      float4 t4 = *reinterpret_cast<const float4*>(&Wt[(size_t)g * DH_ + c]);
      s4v h;
      h[0] = f2bf(0.48f * p4.x + 0.32f * t4.x + ((c + 0) == g ? 0.2f : 0.f));
      h[1] = f2bf(0.48f * p4.y + 0.32f * t4.y + ((c + 1) == g ? 0.2f : 0.f));
      h[2] = f2bf(0.48f * p4.z + 0.32f * t4.z + ((c + 2) == g ? 0.2f : 0.f));
      h[3] = f2bf(0.48f * p4.w + 0.32f * t4.w + ((c + 3) == g ? 0.2f : 0.f));
      *reinterpret_cast<s4v*>(&Ws[g][c]) = h;
    }
  }
  __syncthreads();

  s8v av[4];
#pragma unroll
  for (int ks = 0; ks < 4; ks++)
    av[ks] = *reinterpret_cast<const s8v*>(&vw[(size_t)(r0 + wv * 16 + lrow) * DH_ + ks * 32 + lgrp * 8]);

  f4v acc[8];
#pragma unroll
  for (int i = 0; i < 8; i++) acc[i] = (f4v){0.f, 0.f, 0.f, 0.f};
#pragma unroll
  for (int ks = 0; ks < 4; ks++)
#pragma unroll
    for (int nf = 0; nf < 8; nf++) {
      s8v b = *reinterpret_cast<const s8v*>(&Ws[nf * 16 + lrow][ks * 32 + lgrp * 8]);
      acc[nf] = __builtin_amdgcn_mfma_f32_16x16x32_bf16(av[ks], b, acc[nf], 0, 0, 0);
    }

  const int grow = r0 + wv * 16 + lgrp * 4;
  const int bb = grow >> 12, s = grow & (S_ - 1);
#pragma unroll
  for (int nf = 0; nf < 8; nf++) {
    int g = nf * 16 + lrow;
    float4 v4 = make_float4(acc[nf][0], acc[nf][1], acc[nf][2], acc[nf][3]);
    *reinterpret_cast<float4*>(&cvt[((size_t)(bb * DH_ + g)) * S_ + s]) = v4;
  }
}

// ---------------- cv2t[row][s] = bf16(0.3 cvt[s] + 0.49 cvt[s+1] + 0.21 cvt[s+1024]) ----------------
__global__ void cv2t_kernel(const float* __restrict__ cvt, short* __restrict__ cv2t) {
  int id = blockIdx.x * 256 + threadIdx.x;      // B*DH*S/4 = 524288
  int s = (id & 1023) * 4;
  int row = id >> 10;                            // 512 rows
  const float* src = cvt + (size_t)row * S_;
  float4 a = *reinterpret_cast<const float4*>(src + s);
  float b1 = src[(s + 4) & (S_ - 1)];
  float4 c = *reinterpret_cast<const float4*>(src + ((s + 1024) & (S_ - 1)));
  s4v o;
  o[0] = f2bf(0.3f * a.x + 0.49f * a.y + 0.21f * c.x);
  o[1] = f2bf(0.3f * a.y + 0.49f * a.z + 0.21f * c.y);
  o[2] = f2bf(0.3f * a.z + 0.49f * a.w + 0.21f * c.z);
  o[3] = f2bf(0.3f * a.w + 0.49f * b1  + 0.21f * c.w);
  *reinterpret_cast<s4v*>(&cv2t[(size_t)row * S_ + s]) = o;
}

// ---------------- pass A: column-split softmax denominators (no max tracking; base-2) ----------------
__global__ __launch_bounds__(256) void stats_kernel(const short* __restrict__ qw,
                                                    const short* __restrict__ kw,
                                                    float* __restrict__ spart) {
  const int tid = threadIdx.x;
  const int wv = tid >> 6, lane = tid & 63;
  const int lrow = lane & 15, lgrp = lane >> 4;
  const int b = blockIdx.x >> 3, cq = blockIdx.x & 7;
  const int qt = blockIdx.y;
  const int rowbase = qt * 64 + wv * 16;
  const short* qb = qw + (size_t)b * S_ * DH_;
  const short* kb = kw + (size_t)b * S_ * DH_;

  s8v qa[4];
#pragma unroll
  for (int ks = 0; ks < 4; ks++)
    qa[ks] = *reinterpret_cast<const s8v*>(&qb[(size_t)(rowbase + lrow) * DH_ + ks * 32 + lgrp * 8]);

  float ll[4] = {0.f, 0.f, 0.f, 0.f};

  for (int ct = 0; ct < 8; ct++) {
    int c0 = cq * 512 + ct * 64;
    f4v sacc[4];
#pragma unroll
    for (int i = 0; i < 4; i++) sacc[i] = (f4v){0.f, 0.f, 0.f, 0.f};
#pragma unroll
    for (int nf = 0; nf < 4; nf++) {
      const short* krow = kb + (size_t)(c0 + nf * 16 + lrow) * DH_;
#pragma unroll
      for (int ks = 0; ks < 4; ks++) {
        s8v bf = *reinterpret_cast<const s8v*>(krow + ks * 32 + lgrp * 8);
        sacc[nf] = __builtin_amdgcn_mfma_f32_16x16x32_bf16(qa[ks], bf, sacc[nf], 0, 0, 0);
      }
    }
#pragma unroll
    for (int r = 0; r < 4; r++) {
      ll[r] += fexp2(sacc[0][r] * SCALE2) + fexp2(sacc[1][r] * SCALE2)
             + fexp2(sacc[2][r] * SCALE2) + fexp2(sacc[3][r] * SCALE2);
    }
  }
#pragma unroll
  for (int r = 0; r < 4; r++) {
#pragma unroll
    for (int off = 1; off < 16; off <<= 1) ll[r] += __shfl_xor(ll[r], off);
  }
  if (lrow == 0) {
#pragma unroll
    for (int r = 0; r < 4; r++) {
      int row = rowbase + lgrp * 4 + r;
      spart[((size_t)b * S_ + row) * 8 + cq] = ll[r];
    }
  }
}

__global__ void statcomb_kernel(const float* __restrict__ spart, float* __restrict__ statf) {
  int row = blockIdx.x * 256 + threadIdx.x; // 16384 rows
  float L = 0.f;
#pragma unroll
  for (int i = 0; i < 8; i++) L += spart[(size_t)row * 8 + i];
  statf[row] = 1.0f / L;
}

// ---------------- pass B: stripe-cycled vortex_attn write + out accumulation ----------------
// Block covers positions [pc*128, pc*128+128) in each of the 4 stripes {j*1024}.
// vout[c] = 0.3 p[c] + 0.49 p[c-1] + 0.21 p[c-1024]; stripe j-1 term = previous stripe's registers.
__global__ __launch_bounds__(256) void vortex_kernel(const short* __restrict__ qw,
                                                     const short* __restrict__ kw,
                                                     const short* __restrict__ cv2t,
                                                     const float* __restrict__ statf,
                                                     float* __restrict__ vout,
                                                     float* __restrict__ outp) {
  __shared__ short Pt[4][4096]; // per-wave 16 rows x 256 cols bf16, XOR-swizzled
  const int tid = threadIdx.x;
  const int wv = tid >> 6, lane = tid & 63;
  const int lrow = lane & 15, lgrp = lane >> 4;
  const int lastlane = (lane & 48) | 15;
  const int pc = blockIdx.x, qt = blockIdx.y, b = blockIdx.z;
  const int rowb = qt * 64 + wv * 16;

  const short* qb = qw + (size_t)b * S_ * DH_;
  const short* kb = kw + (size_t)b * S_ * DH_;
  short* P = Pt[wv];

  s8v qa[4];
#pragma unroll
  for (int ks = 0; ks < 4; ks++)
    qa[ks] = *reinterpret_cast<const s8v*>(&qb[(size_t)(rowb + lrow) * DH_ + ks * 32 + lgrp * 8]);

  float rcl[4];
  float* vb[4];
#pragma unroll
  for (int r = 0; r < 4; r++) {
    int row = rowb + lgrp * 4 + r;
    rcl[r] = statf[(size_t)b * S_ + row];
    vb[r] = vout + ((size_t)(b * S_ + row)) * S_;
  }

  f4v o[8];
#pragma unroll
  for (int i = 0; i < 8; i++) o[i] = (f4v){0.f, 0.f, 0.f, 0.f};

  for (int it = 0; it < 2; it++) {
    const int pos0 = pc * 128 + it * 64;
    float ps_[4][4], pp_[4][4], bs0[4];
#pragma unroll
    for (int j = 0; j < 4; j++) {
      const int c0 = j * 1024 + pos0;
      // boundary fragment: cols c0-16 .. c0-1 (wrapped); need col c0-1
      f4v pacc = (f4v){0.f, 0.f, 0.f, 0.f};
      {
        const short* kr = kb + (size_t)((c0 - 16 + lrow) & (S_ - 1)) * DH_;
#pragma unroll
        for (int ks = 0; ks < 4; ks++) {
          s8v bf = *reinterpret_cast<const s8v*>(kr + ks * 32 + lgrp * 8);
          pacc = __builtin_amdgcn_mfma_f32_16x16x32_bf16(qa[ks], bf, pacc, 0, 0, 0);
        }
      }
      float bsh[4];
#pragma unroll
      for (int r = 0; r < 4; r++) {
        float pbv = fexp2(pacc[r] * SCALE2) * rcl[r];
        bsh[r] = __shfl(pbv, lastlane);
      }
      // main 4 fragments (64 cols of stripe j)
      f4v sa[4];
#pragma unroll
      for (int i = 0; i < 4; i++) sa[i] = (f4v){0.f, 0.f, 0.f, 0.f};
#pragma unroll
      for (int nf = 0; nf < 4; nf++) {
        const short* kr = kb + (size_t)(c0 + nf * 16 + lrow) * DH_;
#pragma unroll
        for (int ks = 0; ks < 4; ks++) {
          s8v bf = *reinterpret_cast<const s8v*>(kr + ks * 32 + lgrp * 8);
          sa[nf] = __builtin_amdgcn_mfma_f32_16x16x32_bf16(qa[ks], bf, sa[nf], 0, 0, 0);
        }
      }
      float pcur[4][4];
#pragma unroll
      for (int nf = 0; nf < 4; nf++)
#pragma unroll
        for (int r = 0; r < 4; r++) {
          pcur[nf][r] = fexp2(sa[nf][r] * SCALE2) * rcl[r];
          int row = lgrp * 4 + r, col = j * 64 + nf * 16 + lrow;
          P[row * 256 + (col ^ ((row & 7) << 3))] = f2bf(pcur[nf][r]);
        }
      if (j == 0) {
#pragma unroll
        for (int nf = 0; nf < 4; nf++)
#pragma unroll
          for (int r = 0; r < 4; r++) ps_[nf][r] = pcur[nf][r];
#pragma unroll
        for (int r = 0; r < 4; r++) bs0[r] = bsh[r];
      } else {
#pragma unroll
        for (int nf = 0; nf < 4; nf++)
#pragma unroll
          for (int r = 0; r < 4; r++) {
            float left = __shfl_up(pcur[nf][r], 1);
            float pl = (nf == 0) ? bsh[r] : __shfl(pcur[nf - 1][r], lastlane);
            float sh = (lrow == 0) ? pl : left;
            float val = 0.3f * pcur[nf][r] + 0.49f * sh + 0.21f * pp_[nf][r];
            __builtin_nontemporal_store(val, vb[r] + c0 + nf * 16 + lrow);
          }
      }
#pragma unroll
      for (int nf = 0; nf < 4; nf++)
#pragma unroll
        for (int r = 0; r < 4; r++) pp_[nf][r] = pcur[nf][r];
    }
    // emit stripe 0 (prev = stripe 3 now in pp_)
#pragma unroll
    for (int nf = 0; nf < 4; nf++)
#pragma unroll
      for (int r = 0; r < 4; r++) {
        float left = __shfl_up(ps_[nf][r], 1);
        float pl = (nf == 0) ? bs0[r] : __shfl(ps_[nf - 1][r], lastlane);
        float sh = (lrow == 0) ? pl : left;
        float val = 0.3f * ps_[nf][r] + 0.49f * sh + 0.21f * pp_[nf][r];
        __builtin_nontemporal_store(val, vb[r] + pos0 + nf * 16 + lrow);
      }
    // PV: o += P @ cv2 over this iteration's 256 k-columns
#pragma unroll
    for (int ks2 = 0; ks2 < 8; ks2++) {
      s8v a = *reinterpret_cast<const s8v*>(
          &P[lrow * 256 + (((ks2 * 32) + lgrp * 8) ^ ((lrow & 7) << 3))]);
      const int gcol = (ks2 >> 1) * 1024 + pos0 + (ks2 & 1) * 32 + lgrp * 8;
#pragma unroll
      for (int gf = 0; gf < 8; gf++) {
        s8v bf = *reinterpret_cast<const s8v*>(
            &cv2t[((size_t)(b * DH_ + gf * 16 + lrow)) * S_ + gcol]);
        o[gf] = __builtin_amdgcn_mfma_f32_16x16x32_bf16(a, bf, o[gf], 0, 0, 0);
      }
    }
  }
#pragma unroll
  for (int gf = 0; gf < 8; gf++)
#pragma unroll
    for (int r = 0; r < 4; r++)
      atomicAdd(&outp[((size_t)(b * S_ + rowb + lgrp * 4 + r)) * DH_ + gf * 16 + lrow], o[gf][r]);
}

// ---------------- gate GEMM + final blend ----------------
__global__ __launch_bounds__(256) void gate_kernel(const float* __restrict__ outp,
                                                   const float* __restrict__ prev,
                                                   const short* __restrict__ wmb,
                                                   const float* __restrict__ bm,
                                                   float* __restrict__ dout) {
  __shared__ short As[64][264];
  const int tid = threadIdx.x;
  const int wv = tid >> 6, lane = tid & 63;
  const int lrow = lane & 15, lgrp = lane >> 4;
  const int r0 = blockIdx.x * 64;
  {
    int row = tid >> 2, seg = (tid & 3) * 64;
#pragma unroll
    for (int i = 0; i < 16; i++) {
      int c = seg + i * 4;
      float4 v;
      if (c < 128) v = *reinterpret_cast<const float4*>(&outp[(size_t)(r0 + row) * DH_ + c]);
      else         v = *reinterpret_cast<const float4*>(&prev[(size_t)(r0 + row) * DH_ + (c - 128)]);
      s4v h; h[0] = f2bf(v.x); h[1] = f2bf(v.y); h[2] = f2bf(v.z); h[3] = f2bf(v.w);
      *reinterpret_cast<s4v*>(&As[row][c]) = h;
    }
  }
  __syncthreads();
  f4v g[8];
#pragma unroll
  for (int i = 0; i < 8; i++) g[i] = (f4v){0.f, 0.f, 0.f, 0.f};
#pragma unroll
  for (int ks = 0; ks < 8; ks++) {
    s8v a = *reinterpret_cast<const s8v*>(&As[wv * 16 + lrow][ks * 32 + lgrp * 8]);
#pragma unroll
    for (int nf = 0; nf < 8; nf++) {
      s8v bfr = *reinterpret_cast<const s8v*>(&wmb[(size_t)(nf * 16 + lrow) * 256 + ks * 32 + lgrp * 8]);
      g[nf] = __builtin_amdgcn_mfma_f32_16x16x32_bf16(a, bfr, g[nf], 0, 0, 0);
    }
  }
#pragma unroll
  for (int nf = 0; nf < 8; nf++)
#pragma unroll
    for (int r = 0; r < 4; r++) {
      int h = nf * 16 + lrow;
      int row = r0 + wv * 16 + lgrp * 4 + r;
      float pre = g[nf][r] + bm[h];
      float gate = 1.0f / (1.0f + fexp2(-1.4426950408889634f * pre));
      float op = outp[(size_t)row * DH_ + h];
      float pv = prev[(size_t)row * DH_ + h];
      dout[(size_t)row * DH_ + h] = 0.9f * gate * pv + 0.1f * op;
    }
}

extern "C" void kernel_launch(void* const* d_in, const int* in_sizes, int n_in,
                              void* d_out, int out_size, void* d_ws, size_t ws_size,
                              hipStream_t stream) {
  (void)in_sizes; (void)n_in; (void)out_size; (void)ws_size;
  const float* query = (const float*)d_in[0];
  const float* key   = (const float*)d_in[1];
  const float* value = (const float*)d_in[2];
  const float* prev  = (const float*)d_in[3];
  const float* Wq = (const float*)d_in[4];
  const float* Wk = (const float*)d_in[5];
  const float* Wv = (const float*)d_in[6];
  const float* Wp = (const float*)d_in[7];
  const float* Wt = (const float*)d_in[8];
  const float* Wm = (const float*)d_in[9];
  const float* bm = (const float*)d_in[10];

  char* ws = (char*)d_ws;
  short* qw    = (short*)(ws);                  // [B*S,128] bf16   4 MB
  short* kw    = (short*)(ws + 4194304);        // [B*S,128] bf16   4 MB
  short* vw    = (short*)(ws + 8388608);        // [B*S,128] bf16   4 MB
  float* cvt   = (float*)(ws + 12582912);       // [B*128,S] f32    8 MB (transposed cv)
  short* cv2t  = (short*)(ws + 20971520);       // [B*128,S] bf16   4 MB
  float* spart = (float*)(ws + 25165824);       // [B*S,8]   f32    512 KB
  float* statf = (float*)(ws + 25690112);       // [B*S]     f32    64 KB
  short* wmb   = (short*)(ws + 25755648);       // [128,256] bf16   64 KB
  float* outp  = (float*)(ws + 25821184);       // [B*S,128] f32    8 MB

  float* out_final  = (float*)d_out;
  float* vortex_out = (float*)d_out + (size_t)B_ * S_ * DH_;

  prep_kernel<<<2048, 256, 0, stream>>>(Wm, wmb, (float4*)outp);
  proj3_kernel<<<dim3(256, 3), 256, 0, stream>>>(query, key, value, Wq, Wk, Wv, qw, kw, vw);
  cv_kernel<<<256, 256, 0, stream>>>(vw, Wp, Wt, cvt);
  cv2t_kernel<<<2048, 256, 0, stream>>>(cvt, cv2t);
  stats_kernel<<<dim3(32, 64), 256, 0, stream>>>(qw, kw, spart);
  statcomb_kernel<<<64, 256, 0, stream>>>(spart, statf);
  vortex_kernel<<<dim3(8, 64, B_), 256, 0, stream>>>(qw, kw, cv2t, statf, vortex_out, outp);
  gate_kernel<<<256, 256, 0, stream>>>(outp, prev, wmb, bm, out_final);
}

// Round 6
// 715.831 us; speedup vs baseline: 1.4352x; 1.3273x over previous
//
#include <hip/hip_runtime.h>
#include <hip/hip_bf16.h>

#define B_ 4
#define S_ 4096
#define D_ 1024
#define DH_ 128

static constexpr float SCALE2 = 0.08838834764831845f * 1.4426950408889634f; // log2(e)/sqrt(DH)

typedef __attribute__((ext_vector_type(8))) short s8v;   // 8 bf16
typedef __attribute__((ext_vector_type(4))) short s4v;   // 4 bf16
typedef __attribute__((ext_vector_type(4))) float f4v;   // MFMA acc / float4

__device__ __forceinline__ short f2bf(float f) {
  __hip_bfloat16 h = __float2bfloat16(f);
  return *reinterpret_cast<short*>(&h);
}

#if __has_builtin(__builtin_amdgcn_exp2f)
__device__ __forceinline__ float fexp2(float x) { return __builtin_amdgcn_exp2f(x); }
#else
__device__ __forceinline__ float fexp2(float x) { return __expf(x * 0.6931471805599453f); }
#endif

typedef __attribute__((address_space(1))) const void gvoid;
typedef __attribute__((address_space(3))) void svoid;
__device__ __forceinline__ void gld16(const short* g, short* l) {
  __builtin_amdgcn_global_load_lds((gvoid*)g, (svoid*)l, 16, 0, 0);
}

// Stage 64 K-rows [c0..c0+63] x 128dh (bf16) into dst (LDS, row-major 256B rows,
// 16B chunks XOR-swizzled: logical chunk c of row R lives at slot c ^ (R&7)).
// Achieved by pre-swizzling the per-lane GLOBAL source; LDS dest stays linear.
__device__ __forceinline__ void stageK(const short* kb, int c0, short* dst, int wv, int lane) {
#pragma unroll
  for (int i = 0; i < 4; i++) {
    const int br = (wv * 4 + i) * 4;          // wave-uniform base row
    const int row = br + (lane >> 4);
    const int gr = (c0 + row) & (S_ - 1);
    const int cs = ((lane & 15) ^ (row & 7)) << 3; // halves
    gld16(kb + (size_t)gr * DH_ + cs, dst + br * DH_);
  }
}

// ---------------- prep: zero outp accumulator + convert Wm to bf16 ----------------
__global__ void prep_kernel(const float* __restrict__ Wm, short* __restrict__ wmb,
                            float4* __restrict__ outp4) {
  int id = blockIdx.x * 256 + threadIdx.x;
  if (id < (B_ * S_ * DH_) / 4) outp4[id] = make_float4(0.f, 0.f, 0.f, 0.f);
  if (id < (DH_ * 2 * DH_) / 4) {
    float4 w = reinterpret_cast<const float4*>(Wm)[id];
    s4v h; h[0] = f2bf(w.x); h[1] = f2bf(w.y); h[2] = f2bf(w.z); h[3] = f2bf(w.w);
    reinterpret_cast<s4v*>(wmb)[id] = h;
  }
}

// ---------------- projections: y[M,128] = X[M,1024] @ W[128,1024]^T (bf16 out) ----------------
__global__ __launch_bounds__(256) void proj3_kernel(const float* __restrict__ Xq,
                                                    const float* __restrict__ Xk,
                                                    const float* __restrict__ Xv,
                                                    const float* __restrict__ Wq,
                                                    const float* __restrict__ Wk,
                                                    const float* __restrict__ Wv,
                                                    short* __restrict__ qw,
                                                    short* __restrict__ kw,
                                                    short* __restrict__ vw) {
  __shared__ short Xs[64][72];
  __shared__ short Ws[128][72];
  const int which = blockIdx.y;
  const float* X; const float* W; short* out;
  if (which == 0)      { X = Xq; W = Wq; out = qw; }
  else if (which == 1) { X = Xk; W = Wk; out = kw; }
  else                 { X = Xv; W = Wv; out = vw; }

  const int tid = threadIdx.x;
  const int wv = tid >> 6, lane = tid & 63;
  const int lrow = lane & 15, lgrp = lane >> 4;
  const int r0 = blockIdx.x * 64;

  f4v acc[8];
#pragma unroll
  for (int i = 0; i < 8; i++) acc[i] = (f4v){0.f, 0.f, 0.f, 0.f};

  for (int kk = 0; kk < D_; kk += 64) {
    {
      int row = tid >> 2, cb = (tid & 3) * 16;
      const float* src = X + (size_t)(r0 + row) * D_ + kk + cb;
#pragma unroll
      for (int i = 0; i < 4; i++) {
        float4 v = *reinterpret_cast<const float4*>(src + i * 4);
        s4v h; h[0] = f2bf(v.x); h[1] = f2bf(v.y); h[2] = f2bf(v.z); h[3] = f2bf(v.w);
        *reinterpret_cast<s4v*>(&Xs[row][cb + i * 4]) = h;
      }
    }
    {
      int row = tid >> 1, cb = (tid & 1) * 32;
      const float* src = W + (size_t)row * D_ + kk + cb;
#pragma unroll
      for (int i = 0; i < 8; i++) {
        float4 v = *reinterpret_cast<const float4*>(src + i * 4);
        s4v h; h[0] = f2bf(v.x); h[1] = f2bf(v.y); h[2] = f2bf(v.z); h[3] = f2bf(v.w);
        *reinterpret_cast<s4v*>(&Ws[row][cb + i * 4]) = h;
      }
    }
    __syncthreads();
#pragma unroll
    for (int ks = 0; ks < 2; ks++) {
      s8v a = *reinterpret_cast<const s8v*>(&Xs[wv * 16 + lrow][ks * 32 + lgrp * 8]);
#pragma unroll
      for (int nf = 0; nf < 8; nf++) {
        s8v b = *reinterpret_cast<const s8v*>(&Ws[nf * 16 + lrow][ks * 32 + lgrp * 8]);
        acc[nf] = __builtin_amdgcn_mfma_f32_16x16x32_bf16(a, b, acc[nf], 0, 0, 0);
      }
    }
    __syncthreads();
  }
#pragma unroll
  for (int nf = 0; nf < 8; nf++)
#pragma unroll
    for (int r = 0; r < 4; r++) {
      int row = r0 + wv * 16 + lgrp * 4 + r;
      out[(size_t)row * DH_ + nf * 16 + lrow] = f2bf(acc[nf][r]);
    }
}

// ---------------- cvt[b*128+g][s] = (v @ (0.2 I + 0.48 Wp + 0.32 Wt)^T)^T  (f32, transposed) ----------------
__global__ __launch_bounds__(256) void cv_kernel(const short* __restrict__ vw,
                                                 const float* __restrict__ Wp,
                                                 const float* __restrict__ Wt,
                                                 float* __restrict__ cvt) {
  __shared__ short Ws[128][136];
  const int tid = threadIdx.x;
  const int wv = tid >> 6, lane = tid & 63;
  const int lrow = lane & 15, lgrp = lane >> 4;
  const int r0 = blockIdx.x * 64;

  {
    int g = tid >> 1, cb = (tid & 1) * 64;
#pragma unroll
    for (int i = 0; i < 16; i++) {
      int c = cb + i * 4;
      float4 p4 = *reinterpret_cast<const float4*>(&Wp[(size_t)g * DH_ + c]);
      float4 t4 = *reinterpret_cast<const float4*>(&Wt[(size_t)g * DH_ + c]);
      s4v h;
      h[0] = f2bf(0.48f * p4.x + 0.32f * t4.x + ((c + 0) == g ? 0.2f : 0.f));
      h[1] = f2bf(0.48f * p4.y + 0.32f * t4.y + ((c + 1) == g ? 0.2f : 0.f));
      h[2] = f2bf(0.48f * p4.z + 0.32f * t4.z + ((c + 2) == g ? 0.2f : 0.f));
      h[3] = f2bf(0.48f * p4.w + 0.32f * t4.w + ((c + 3) == g ? 0.2f : 0.f));
      *reinterpret_cast<s4v*>(&Ws[g][c]) = h;
    }
  }
  __syncthreads();

  s8v av[4];
#pragma unroll
  for (int ks = 0; ks < 4; ks++)
    av[ks] = *reinterpret_cast<const s8v*>(&vw[(size_t)(r0 + wv * 16 + lrow) * DH_ + ks * 32 + lgrp * 8]);

  f4v acc[8];
#pragma unroll
  for (int i = 0; i < 8; i++) acc[i] = (f4v){0.f, 0.f, 0.f, 0.f};
#pragma unroll
  for (int ks = 0; ks < 4; ks++)
#pragma unroll
    for (int nf = 0; nf < 8; nf++) {
      s8v b = *reinterpret_cast<const s8v*>(&Ws[nf * 16 + lrow][ks * 32 + lgrp * 8]);
      acc[nf] = __builtin_amdgcn_mfma_f32_16x16x32_bf16(av[ks], b, acc[nf], 0, 0, 0);
    }

  const int grow = r0 + wv * 16 + lgrp * 4;
  const int bb = grow >> 12, s = grow & (S_ - 1);
#pragma unroll
  for (int nf = 0; nf < 8; nf++) {
    int g = nf * 16 + lrow;
    float4 v4 = make_float4(acc[nf][0], acc[nf][1], acc[nf][2], acc[nf][3]);
    *reinterpret_cast<float4*>(&cvt[((size_t)(bb * DH_ + g)) * S_ + s]) = v4;
  }
}

// ---------------- cv2t[row][s] = bf16(0.3 cvt[s] + 0.49 cvt[s+1] + 0.21 cvt[s+1024]) ----------------
__global__ void cv2t_kernel(const float* __restrict__ cvt, short* __restrict__ cv2t) {
  int id = blockIdx.x * 256 + threadIdx.x;      // B*DH*S/4 = 524288
  int s = (id & 1023) * 4;
  int row = id >> 10;                            // 512 rows
  const float* src = cvt + (size_t)row * S_;
  float4 a = *reinterpret_cast<const float4*>(src + s);
  float b1 = src[(s + 4) & (S_ - 1)];
  float4 c = *reinterpret_cast<const float4*>(src + ((s + 1024) & (S_ - 1)));
  s4v o;
  o[0] = f2bf(0.3f * a.x + 0.49f * a.y + 0.21f * c.x);
  o[1] = f2bf(0.3f * a.y + 0.49f * a.z + 0.21f * c.y);
  o[2] = f2bf(0.3f * a.z + 0.49f * a.w + 0.21f * c.z);
  o[3] = f2bf(0.3f * a.w + 0.49f * b1  + 0.21f * c.w);
  *reinterpret_cast<s4v*>(&cv2t[(size_t)row * S_ + s]) = o;
}

// ---------------- pass A: column-split softmax denominators (staged K, 2-phase pipeline) ----------------
__global__ __launch_bounds__(256) void stats_kernel(const short* __restrict__ qw,
                                                    const short* __restrict__ kw,
                                                    float* __restrict__ spart) {
  __shared__ short Kt[2][64 * DH_]; // 32 KB double-buffered K tile
  const int tid = threadIdx.x;
  const int wv = tid >> 6, lane = tid & 63;
  const int lrow = lane & 15, lgrp = lane >> 4;
  const int b = blockIdx.x >> 3, cq = blockIdx.x & 7;
  const int qt = blockIdx.y;
  const int rowbase = qt * 64 + wv * 16;
  const short* qb = qw + (size_t)b * S_ * DH_;
  const short* kb = kw + (size_t)b * S_ * DH_;

  s8v qa[4];
#pragma unroll
  for (int ks = 0; ks < 4; ks++)
    qa[ks] = *reinterpret_cast<const s8v*>(&qb[(size_t)(rowbase + lrow) * DH_ + ks * 32 + lgrp * 8]);

  float ll[4] = {0.f, 0.f, 0.f, 0.f};

  stageK(kb, cq * 512, Kt[0], wv, lane);
  __syncthreads();

  for (int ct = 0; ct < 8; ct++) {
    const int c0 = cq * 512 + ct * 64;
    short* Ktc = Kt[ct & 1];
    if (ct < 7) stageK(kb, c0 + 64, Kt[(ct + 1) & 1], wv, lane);

    f4v sacc[4];
#pragma unroll
    for (int i = 0; i < 4; i++) sacc[i] = (f4v){0.f, 0.f, 0.f, 0.f};
#pragma unroll
    for (int nf = 0; nf < 4; nf++) {
      const int lr = nf * 16 + lrow;
#pragma unroll
      for (int ks = 0; ks < 4; ks++) {
        s8v bf = *reinterpret_cast<const s8v*>(&Ktc[lr * DH_ + ((((ks << 2) + lgrp) ^ (lr & 7)) << 3)]);
        sacc[nf] = __builtin_amdgcn_mfma_f32_16x16x32_bf16(qa[ks], bf, sacc[nf], 0, 0, 0);
      }
    }
#pragma unroll
    for (int r = 0; r < 4; r++) {
      ll[r] += fexp2(sacc[0][r] * SCALE2) + fexp2(sacc[1][r] * SCALE2)
             + fexp2(sacc[2][r] * SCALE2) + fexp2(sacc[3][r] * SCALE2);
    }
    __syncthreads();
  }
#pragma unroll
  for (int r = 0; r < 4; r++) {
#pragma unroll
    for (int off = 1; off < 16; off <<= 1) ll[r] += __shfl_xor(ll[r], off);
  }
  if (lrow == 0) {
#pragma unroll
    for (int r = 0; r < 4; r++) {
      int row = rowbase + lgrp * 4 + r;
      spart[((size_t)b * S_ + row) * 8 + cq] = ll[r];
    }
  }
}

__global__ void statcomb_kernel(const float* __restrict__ spart, float* __restrict__ statf) {
  int row = blockIdx.x * 256 + threadIdx.x; // 16384 rows
  float L = 0.f;
#pragma unroll
  for (int i = 0; i < 8; i++) L += spart[(size_t)row * 8 + i];
  statf[row] = 1.0f / L;
}

// ---------------- pass B: stripe-cycled vortex_attn + PV, staged K, 2-phase pipeline ----------------
__global__ __launch_bounds__(256) void vortex_kernel(const short* __restrict__ qw,
                                                     const short* __restrict__ kw,
                                                     const short* __restrict__ cv2t,
                                                     const float* __restrict__ statf,
                                                     float* __restrict__ vout,
                                                     float* __restrict__ outp) {
  __shared__ short Kt[2][64 * DH_];          // 32 KB double-buffered K tile
  __shared__ __align__(16) char Ubuf[4][4352]; // per-wave union: P bf16[16][64] | Vst f32[16][68]
  const int tid = threadIdx.x;
  const int wv = tid >> 6, lane = tid & 63;
  const int lrow = lane & 15, lgrp = lane >> 4;
  const int lastlane = (lane & 48) | 15;
  const int pc = blockIdx.x, qt = blockIdx.y, b = blockIdx.z;
  const int rowb = qt * 64 + wv * 16;

  const short* qb = qw + (size_t)b * S_ * DH_;
  const short* kb = kw + (size_t)b * S_ * DH_;
  short* P = (short*)&Ubuf[wv][0];
  float* V = (float*)&Ubuf[wv][0];
  float* voutB = vout + ((size_t)(b * S_ + rowb)) * S_;

  s8v qa[4];
#pragma unroll
  for (int ks = 0; ks < 4; ks++)
    qa[ks] = *reinterpret_cast<const s8v*>(&qb[(size_t)(rowb + lrow) * DH_ + ks * 32 + lgrp * 8]);

  float rcl[4];
#pragma unroll
  for (int r = 0; r < 4; r++) rcl[r] = statf[(size_t)b * S_ + rowb + lgrp * 4 + r];

  f4v o[8];
#pragma unroll
  for (int i = 0; i < 8; i++) o[i] = (f4v){0.f, 0.f, 0.f, 0.f};

  float carry[4][4], ps_[4][4], pp_[4][4], bs0[4];

  // emit one 16x64 tile of vortex_attn through LDS for coalesced 16B stores
  auto emitV = [&](const float (&pcv)[4][4], const float (&ppv)[4][4],
                   const float (&bshv)[4], int c0e) {
#pragma unroll
    for (int nf = 0; nf < 4; nf++)
#pragma unroll
      for (int r = 0; r < 4; r++) {
        float left = __shfl_up(pcv[nf][r], 1);
        float pl = (nf == 0) ? bshv[r] : __shfl(pcv[nf - 1][r], lastlane);
        float sh = (lrow == 0) ? pl : left;
        V[(lgrp * 4 + r) * 68 + nf * 16 + lrow] =
            0.3f * pcv[nf][r] + 0.49f * sh + 0.21f * ppv[nf][r];
      }
#pragma unroll
    for (int p = 0; p < 4; p++) {
      int row = p * 4 + (lane >> 4);
      f4v t = *reinterpret_cast<const f4v*>(&V[row * 68 + (lane & 15) * 4]);
      __builtin_nontemporal_store(
          t, reinterpret_cast<f4v*>(voutB + (size_t)row * S_ + c0e + (lane & 15) * 4));
    }
  };

  stageK(kb, pc * 128, Kt[0], wv, lane);
  __syncthreads();

#pragma unroll
  for (int s = 0; s < 8; s++) {
    const int it = s >> 2, j = s & 3;
    const int c0 = j * 1024 + pc * 128 + it * 64;
    short* Ktc = Kt[s & 1];
    if (s < 7) {
      const int c0n = ((s + 1) & 3) * 1024 + pc * 128 + ((s + 1) >> 2) * 64;
      stageK(kb, c0n, Kt[(s + 1) & 1], wv, lane);
    }

    // boundary column c0-1 (it=0 only; it=1 reuses carry from it=0)
    float bsh[4];
    if (it == 0) {
      const short* krB = kb + (size_t)((c0 - 16 + lrow) & (S_ - 1)) * DH_;
      f4v pacc = (f4v){0.f, 0.f, 0.f, 0.f};
#pragma unroll
      for (int ks = 0; ks < 4; ks++) {
        s8v bf = *reinterpret_cast<const s8v*>(krB + ks * 32 + lgrp * 8);
        pacc = __builtin_amdgcn_mfma_f32_16x16x32_bf16(qa[ks], bf, pacc, 0, 0, 0);
      }
#pragma unroll
      for (int r = 0; r < 4; r++) {
        float pbv = fexp2(pacc[r] * SCALE2) * rcl[r];
        bsh[r] = __shfl(pbv, lastlane);
      }
    } else {
#pragma unroll
      for (int r = 0; r < 4; r++) bsh[r] = carry[j][r];
    }

    // main 64 columns from staged LDS tile
    f4v sa[4];
#pragma unroll
    for (int i = 0; i < 4; i++) sa[i] = (f4v){0.f, 0.f, 0.f, 0.f};
#pragma unroll
    for (int nf = 0; nf < 4; nf++) {
      const int lr = nf * 16 + lrow;
#pragma unroll
      for (int ks = 0; ks < 4; ks++) {
        s8v bf = *reinterpret_cast<const s8v*>(&Ktc[lr * DH_ + ((((ks << 2) + lgrp) ^ (lr & 7)) << 3)]);
        sa[nf] = __builtin_amdgcn_mfma_f32_16x16x32_bf16(qa[ks], bf, sa[nf], 0, 0, 0);
      }
    }
    float pcur[4][4];
#pragma unroll
    for (int nf = 0; nf < 4; nf++)
#pragma unroll
      for (int r = 0; r < 4; r++) pcur[nf][r] = fexp2(sa[nf][r] * SCALE2) * rcl[r];

    if (it == 0) {
#pragma unroll
      for (int r = 0; r < 4; r++) carry[j][r] = __shfl(pcur[3][r], lastlane);
    }

    // P tile (bf16, XOR-swizzled) for PV A-operand
#pragma unroll
    for (int nf = 0; nf < 4; nf++)
#pragma unroll
      for (int r = 0; r < 4; r++) {
        int row = lgrp * 4 + r;
        P[row * 64 + ((nf * 16 + lrow) ^ ((row & 7) << 3))] = f2bf(pcur[nf][r]);
      }
    // PV: o += P @ cv2 over this step's 64 k-columns
#pragma unroll
    for (int ks2 = 0; ks2 < 2; ks2++) {
      s8v a = *reinterpret_cast<const s8v*>(
          &P[lrow * 64 + (((ks2 << 5) + (lgrp << 3)) ^ ((lrow & 7) << 3))]);
#pragma unroll
      for (int gf = 0; gf < 8; gf++) {
        s8v bf = *reinterpret_cast<const s8v*>(
            &cv2t[((size_t)(b * DH_ + gf * 16 + lrow)) * S_ + c0 + ks2 * 32 + lgrp * 8]);
        o[gf] = __builtin_amdgcn_mfma_f32_16x16x32_bf16(a, bf, o[gf], 0, 0, 0);
      }
    }

    // vortex_attn emission (after PV so the union buffer can be reused)
    if (j == 0) {
#pragma unroll
      for (int nf = 0; nf < 4; nf++)
#pragma unroll
        for (int r = 0; r < 4; r++) ps_[nf][r] = pcur[nf][r];
#pragma unroll
      for (int r = 0; r < 4; r++) bs0[r] = bsh[r];
    } else {
      emitV(pcur, pp_, bsh, c0);
    }
#pragma unroll
    for (int nf = 0; nf < 4; nf++)
#pragma unroll
      for (int r = 0; r < 4; r++) pp_[nf][r] = pcur[nf][r];
    if (j == 3) emitV(ps_, pp_, bs0, c0 - 3072);

    __syncthreads();
  }

#pragma unroll
  for (int gf = 0; gf < 8; gf++)
#pragma unroll
    for (int r = 0; r < 4; r++)
      atomicAdd(&outp[((size_t)(b * S_ + rowb + lgrp * 4 + r)) * DH_ + gf * 16 + lrow], o[gf][r]);
}

// ---------------- gate GEMM + final blend ----------------
__global__ __launch_bounds__(256) void gate_kernel(const float* __restrict__ outp,
                                                   const float* __restrict__ prev,
                                                   const short* __restrict__ wmb,
                                                   const float* __restrict__ bm,
                                                   float* __restrict__ dout) {
  __shared__ short As[64][264];
  const int tid = threadIdx.x;
  const int wv = tid >> 6, lane = tid & 63;
  const int lrow = lane & 15, lgrp = lane >> 4;
  const int r0 = blockIdx.x * 64;
  {
    int row = tid >> 2, seg = (tid & 3) * 64;
#pragma unroll
    for (int i = 0; i < 16; i++) {
      int c = seg + i * 4;
      float4 v;
      if (c < 128) v = *reinterpret_cast<const float4*>(&outp[(size_t)(r0 + row) * DH_ + c]);
      else         v = *reinterpret_cast<const float4*>(&prev[(size_t)(r0 + row) * DH_ + (c - 128)]);
      s4v h; h[0] = f2bf(v.x); h[1] = f2bf(v.y); h[2] = f2bf(v.z); h[3] = f2bf(v.w);
      *reinterpret_cast<s4v*>(&As[row][c]) = h;
    }
  }
  __syncthreads();
  f4v g[8];
#pragma unroll
  for (int i = 0; i < 8; i++) g[i] = (f4v){0.f, 0.f, 0.f, 0.f};
#pragma unroll
  for (int ks = 0; ks < 8; ks++) {
    s8v a = *reinterpret_cast<const s8v*>(&As[wv * 16 + lrow][ks * 32 + lgrp * 8]);
#pragma unroll
    for (int nf = 0; nf < 8; nf++) {
      s8v bfr = *reinterpret_cast<const s8v*>(&wmb[(size_t)(nf * 16 + lrow) * 256 + ks * 32 + lgrp * 8]);
      g[nf] = __builtin_amdgcn_mfma_f32_16x16x32_bf16(a, bfr, g[nf], 0, 0, 0);
    }
  }
#pragma unroll
  for (int nf = 0; nf < 8; nf++)
#pragma unroll
    for (int r = 0; r < 4; r++) {
      int h = nf * 16 + lrow;
      int row = r0 + wv * 16 + lgrp * 4 + r;
      float pre = g[nf][r] + bm[h];
      float gate = 1.0f / (1.0f + fexp2(-1.4426950408889634f * pre));
      float op = outp[(size_t)row * DH_ + h];
      float pv = prev[(size_t)row * DH_ + h];
      dout[(size_t)row * DH_ + h] = 0.9f * gate * pv + 0.1f * op;
    }
}

extern "C" void kernel_launch(void* const* d_in, const int* in_sizes, int n_in,
                              void* d_out, int out_size, void* d_ws, size_t ws_size,
                              hipStream_t stream) {
  (void)in_sizes; (void)n_in; (void)out_size; (void)ws_size;
  const float* query = (const float*)d_in[0];
  const float* key   = (const float*)d_in[1];
  const float* value = (const float*)d_in[2];
  const float* prev  = (const float*)d_in[3];
  const float* Wq = (const float*)d_in[4];
  const float* Wk = (const float*)d_in[5];
  const float* Wv = (const float*)d_in[6];
  const float* Wp = (const float*)d_in[7];
  const float* Wt = (const float*)d_in[8];
  const float* Wm = (const float*)d_in[9];
  const float* bm = (const float*)d_in[10];

  char* ws = (char*)d_ws;
  short* qw    = (short*)(ws);                  // [B*S,128] bf16   4 MB
  short* kw    = (short*)(ws + 4194304);        // [B*S,128] bf16   4 MB
  short* vw    = (short*)(ws + 8388608);        // [B*S,128] bf16   4 MB
  float* cvt   = (float*)(ws + 12582912);       // [B*128,S] f32    8 MB (transposed cv)
  short* cv2t  = (short*)(ws + 20971520);       // [B*128,S] bf16   4 MB
  float* spart = (float*)(ws + 25165824);       // [B*S,8]   f32    512 KB
  float* statf = (float*)(ws + 25690112);       // [B*S]     f32    64 KB
  short* wmb   = (short*)(ws + 25755648);       // [128,256] bf16   64 KB
  float* outp  = (float*)(ws + 25821184);       // [B*S,128] f32    8 MB

  float* out_final  = (float*)d_out;
  float* vortex_out = (float*)d_out + (size_t)B_ * S_ * DH_;

  prep_kernel<<<2048, 256, 0, stream>>>(Wm, wmb, (float4*)outp);
  proj3_kernel<<<dim3(256, 3), 256, 0, stream>>>(query, key, value, Wq, Wk, Wv, qw, kw, vw);
  cv_kernel<<<256, 256, 0, stream>>>(vw, Wp, Wt, cvt);
  cv2t_kernel<<<2048, 256, 0, stream>>>(cvt, cv2t);
  stats_kernel<<<dim3(32, 64), 256, 0, stream>>>(qw, kw, spart);
  statcomb_kernel<<<64, 256, 0, stream>>>(spart, statf);
  vortex_kernel<<<dim3(8, 64, B_), 256, 0, stream>>>(qw, kw, cv2t, statf, vortex_out, outp);
  gate_kernel<<<256, 256, 0, stream>>>(outp, prev, wmb, bm, out_final);
}